// Round 3
// baseline (129.224 us; speedup 1.0000x reference)
//
#include <hip/hip_runtime.h>
#include <stdint.h>

#define LL 256
#define DD 256
#define CH 32

typedef __attribute__((ext_vector_type(2))) _Float16 f16x2;
typedef __attribute__((ext_vector_type(8))) _Float16 halfx8;
typedef __attribute__((ext_vector_type(4))) float f32x4;

static __device__ __forceinline__ uint32_t pk16(float a, float b) {
  f16x2 p; p.x = (_Float16)a; p.y = (_Float16)b;   // RTN casts
  return __builtin_bit_cast(uint32_t, p);
}
static __device__ __forceinline__ f16x2 bc2(uint32_t u) { return __builtin_bit_cast(f16x2, u); }
static __device__ __forceinline__ halfx8 bc8(uint4 u) { return __builtin_bit_cast(halfx8, u); }

// ---------------------------------------------------------------------------
// Kernel P: one-time weight packing (x is no longer pre-converted; kernel A
// converts fp32->f16 in-flight during LDS staging).
//  blocks [0,64):  W1 -> w1p f16 in MFMA-A-frag layout with the d-permutation
//  block 64:       W2 -> w2p packed f16 pairs
// ---------------------------------------------------------------------------
__global__ void bepler_pack(const float* __restrict__ W1, const float* __restrict__ W2,
                            _Float16* __restrict__ w1p, uint32_t* __restrict__ w2p) {
  const int gid = blockIdx.x * 256 + threadIdx.x;
  if (blockIdx.x < 64) {
    const int idx = gid;                   // 0..16383
    const int t  = idx & 7;
    const int l  = (idx >> 3) & 63;
    const int hM = (idx >> 9) & 1;
    const int s  = idx >> 10;
    const int g  = (l >> 4) & 3;
    const int d  = 32 * (s >> 1) + 8 * g + 4 * (s & 1) + 2 * ((t >> 2) & 1) + (t & 1);
    const int ko = (t & 2) ? (DD + d) : d;
    w1p[idx] = (_Float16)W1[ko * CH + 16 * hM + (l & 15)];
  } else {
    for (int k = threadIdx.x; k < 784; k += 256) {
      const int t  = k & 3;
      const int dj = (k >> 2) % 7;
      const int qd = (k >> 2) / 7;         // di*4+q
      const int q  = qd & 3;
      const int di = qd >> 2;
      const int c  = q * 8 + 2 * t;
      w2p[k] = pk16(W2[(di * 7 + dj) * 32 + c], W2[(di * 7 + dj) * 32 + c + 1]);
    }
  }
}

// ---------------------------------------------------------------------------
// Kernel A: h[b,i,j,c] = mask * relu( z . W1[:,c] + b1[c] ), f16 out.
// Length-culled blocks exit immediately. grid.z = 2*B: each block runs half
// of the ip passes (finer load balance; live blocks < 1.5/CU after culling).
// Staging converts fp32 x -> f16 in-flight (bitwise-identical to the old
// pre-pack path; RTN casts).
// ---------------------------------------------------------------------------
#define XPAD 272
__global__ __launch_bounds__(256, 2) void bepler_h_kernel(
    const float* __restrict__ x, const int* __restrict__ plen,
    const uint4* __restrict__ w1p4, const float* __restrict__ b1,
    _Float16* __restrict__ hws)
{
  __shared__ _Float16 xi[32 * XPAD];   // 17.4 KB
  __shared__ _Float16 xj[32 * XPAD];

  const int tid  = threadIdx.x;
  const int lane = tid & 63;
  const int wave = tid >> 6;
  const int b    = blockIdx.z >> 1;
  const int half = blockIdx.z & 1;
  const int i0 = blockIdx.y * 32;
  const int j0 = blockIdx.x * 32;

  const int len = plen[b];
  if (i0 >= len || j0 >= len) return;   // block-uniform: whole tile is masked out

  const int g   = lane >> 4;
  const int m16 = lane & 15;

  // Load all 32 A-fragments from prepacked global (coalesced, L2-hot): 128 VGPR
  uint4 af[16][2];
#pragma unroll
  for (int s = 0; s < 16; ++s) {
#pragma unroll
    for (int hM = 0; hM < 2; ++hM)
      af[s][hM] = w1p4[(s * 2 + hM) * 64 + lane];
  }

  // Stage x tiles: fp32 global -> f16 LDS (coalesced 32B/lane reads)
  const float* xbi = x + ((size_t)b * LL + i0) * DD;
  const float* xbj = x + ((size_t)b * LL + j0) * DD;
  for (int idx = tid; idx < 1024; idx += 256) {
    const int r = idx >> 5, cg = idx & 31;
    const float4* ri = (const float4*)(xbi + r * DD);
    const float4* rj = (const float4*)(xbj + r * DD);
    const float4 fi0 = ri[cg * 2], fi1 = ri[cg * 2 + 1];
    const float4 fj0 = rj[cg * 2], fj1 = rj[cg * 2 + 1];
    uint4 vi, vj;
    vi.x = pk16(fi0.x, fi0.y); vi.y = pk16(fi0.z, fi0.w);
    vi.z = pk16(fi1.x, fi1.y); vi.w = pk16(fi1.z, fi1.w);
    vj.x = pk16(fj0.x, fj0.y); vj.y = pk16(fj0.z, fj0.w);
    vj.z = pk16(fj1.x, fj1.y); vj.w = pk16(fj1.z, fj1.w);
    ((uint4*)(xi + r * XPAD))[cg] = vi;
    ((uint4*)(xj + r * XPAD))[cg] = vj;
  }

  float b1v[2][4];
#pragma unroll
  for (int r = 0; r < 4; ++r) {
    b1v[0][r] = b1[g * 4 + r];
    b1v[1][r] = b1[16 + g * 4 + r];
  }
  __syncthreads();

  for (int ip2 = 0; ip2 < 2; ++ip2) {  // this block's half of the i-row pairs
    const int ip = half * 2 + ip2;
    const int r0 = wave * 8 + 2 * ip;
    const int r1 = r0 + 1;
    f32x4 acc[2][2][2];                  // [rr][jg][hM]
#pragma unroll
    for (int rr = 0; rr < 2; ++rr)
#pragma unroll
      for (int jg = 0; jg < 2; ++jg)
#pragma unroll
        for (int hM = 0; hM < 2; ++hM)
          acc[rr][jg][hM] = (f32x4){0.f, 0.f, 0.f, 0.f};

#pragma unroll
    for (int m = 0; m < 8; ++m) {
      const int doff = 32 * m + 8 * g;
      const uint4 ua0 = *(const uint4*)(xi + r0 * XPAD + doff);  // broadcast b128
      const uint4 ua1 = *(const uint4*)(xi + r1 * XPAD + doff);
#pragma unroll
      for (int jg = 0; jg < 2; ++jg) {
        const uint4 uc = *(const uint4*)(xj + (jg * 16 + m16) * XPAD + doff);
        const f16x2 c0 = bc2(uc.x), c1 = bc2(uc.y), c2 = bc2(uc.z), c3 = bc2(uc.w);
#pragma unroll
        for (int rr = 0; rr < 2; ++rr) {
          const uint4 ua = rr ? ua1 : ua0;
          const f16x2 a0 = bc2(ua.x), a1 = bc2(ua.y), a2 = bc2(ua.z), a3 = bc2(ua.w);
          const f16x2 p0 = a0 * c0, p1 = a1 * c1, p2 = a2 * c2, p3 = a3 * c3;
          const uint32_t s0 = __builtin_bit_cast(uint32_t, a0 - c0) & 0x7FFF7FFFu;
          const uint32_t s1 = __builtin_bit_cast(uint32_t, a1 - c1) & 0x7FFF7FFFu;
          const uint32_t s2 = __builtin_bit_cast(uint32_t, a2 - c2) & 0x7FFF7FFFu;
          const uint32_t s3 = __builtin_bit_cast(uint32_t, a3 - c3) & 0x7FFF7FFFu;
          uint4 be, bo;
          be.x = __builtin_bit_cast(uint32_t, p0); be.y = s0;
          be.z = __builtin_bit_cast(uint32_t, p1); be.w = s1;
          bo.x = __builtin_bit_cast(uint32_t, p2); bo.y = s2;
          bo.z = __builtin_bit_cast(uint32_t, p3); bo.w = s3;
          const halfx8 bE = bc8(be), bO = bc8(bo);
          acc[rr][jg][0] = __builtin_amdgcn_mfma_f32_16x16x32_f16(bc8(af[2 * m][0]),     bE, acc[rr][jg][0], 0, 0, 0);
          acc[rr][jg][1] = __builtin_amdgcn_mfma_f32_16x16x32_f16(bc8(af[2 * m][1]),     bE, acc[rr][jg][1], 0, 0, 0);
          acc[rr][jg][0] = __builtin_amdgcn_mfma_f32_16x16x32_f16(bc8(af[2 * m + 1][0]), bO, acc[rr][jg][0], 0, 0, 0);
          acc[rr][jg][1] = __builtin_amdgcn_mfma_f32_16x16x32_f16(bc8(af[2 * m + 1][1]), bO, acc[rr][jg][1], 0, 0, 0);
        }
      }
    }

    // D layout: c = 16*hM + (lane>>4)*4 + reg ; j = j0 + jg*16 + (lane&15)
#pragma unroll
    for (int rr = 0; rr < 2; ++rr) {
      const int i = i0 + (rr ? r1 : r0);
#pragma unroll
      for (int jg = 0; jg < 2; ++jg) {
        const int j = j0 + jg * 16 + m16;
        const float msk = (i < len && j < len) ? 1.f : 0.f;
        _Float16* hp = hws + ((size_t)(b * LL + i) * LL + j) * CH + g * 4;
#pragma unroll
        for (int hM = 0; hM < 2; ++hM) {
          const f32x4 a = acc[rr][jg][hM];
          uint2 st;
          st.x = pk16(fmaxf(a[0] + b1v[hM][0], 0.f) * msk,
                      fmaxf(a[1] + b1v[hM][1], 0.f) * msk);
          st.y = pk16(fmaxf(a[2] + b1v[hM][2], 0.f) * msk,
                      fmaxf(a[3] + b1v[hM][3], 0.f) * msk);
          *(uint2*)(hp + hM * 16) = st;
        }
      }
    }
  }
}

// ---------------------------------------------------------------------------
// Kernel B: out[b,i,j] = mask * ( sum_{di,dj,c} h[..]*W2[di,dj,c] + b2 )
// 32x32 output tile (4 outputs/thread: rows li, li+16 x cols 2pj, 2pj+1),
// halo 38x38 staged in TWO q-phases (16 ch each) -> LDS 47.4 KB, 3 blocks/CU.
// Halo re-read factor 1.41 (vs 1.63 at 16x32); half the block count.
// Coalesced reads only (no symmetry swap — round-2 lesson).
// ---------------------------------------------------------------------------
#define TR2 38
#define TC2 38
#define TP2 39
__global__ __launch_bounds__(256, 3) void bepler_conv_kernel(
    const _Float16* __restrict__ hws, const uint32_t* __restrict__ w2p,
    const float* __restrict__ b2, const int* __restrict__ plen,
    float* __restrict__ out)
{
  __shared__ _Float16 htile[2 * TR2 * TP2 * 8];   // 47,424 B

  const int tid = threadIdx.x;
  const int b   = blockIdx.z;
  const int i0  = blockIdx.y * 32;
  const int j0  = blockIdx.x * 32;
  const int l    = tid & 63;
  const int wave = tid >> 6;
  const int li = wave * 4 + (l & 3);   // output rows li, li+16
  const int pj = (l >> 2) & 15;        // output cols 2*pj, 2*pj+1

  const int len = plen[b];

  if (i0 >= len || j0 >= len) {        // block-uniform: whole out tile is zero
    float2 z; z.x = 0.f; z.y = 0.f;
    *(float2*)(out + (size_t)(b * LL + i0 + li) * LL + j0 + 2 * pj) = z;
    *(float2*)(out + (size_t)(b * LL + i0 + li + 16) * LL + j0 + 2 * pj) = z;
    return;
  }

  float s[2][2] = {{0.f, 0.f}, {0.f, 0.f}};   // [rowHalf][col]

  for (int ph = 0; ph < 2; ++ph) {     // channel phases: q = 2*ph, 2*ph+1
    for (int idx = tid; idx < TR2 * TC2; idx += 256) {
      const int row = idx / TC2, col = idx - row * TC2;
      const int gi = i0 - 3 + row, gj = j0 - 3 + col;
      uint4 v0 = make_uint4(0u, 0u, 0u, 0u), v1 = v0;
      if (gi >= 0 && gi < len && gj >= 0 && gj < len) {
        const uint4* src = (const uint4*)(hws + (((size_t)(b * LL + gi) * LL + gj) * CH + ph * 16));
        v0 = src[0];
        v1 = src[1];
      }
      *(uint4*)(htile + ((0 * TR2 + row) * TP2 + col) * 8) = v0;
      *(uint4*)(htile + ((1 * TR2 + row) * TP2 + col) * 8) = v1;
    }
    __syncthreads();

    f16x2 a0[2][8], a1[2][8];
#pragma unroll
    for (int rh = 0; rh < 2; ++rh)
#pragma unroll
      for (int t = 0; t < 8; ++t) {
        a0[rh][t] = (f16x2){(_Float16)0, (_Float16)0};
        a1[rh][t] = (f16x2){(_Float16)0, (_Float16)0};
      }

    for (int di = 0; di < 7; ++di) {
#pragma unroll
      for (int rh = 0; rh < 2; ++rh) {
        const int row = li + rh * 16 + di;        // 0..37
#pragma unroll
        for (int qq = 0; qq < 2; ++qq) {
          const _Float16* hrow = htile + ((qq * TR2 + row) * TP2) * 8;
          const uint32_t* wq = w2p + (di * 4 + 2 * ph + qq) * 28;  // uniform -> SGPR
#pragma unroll
          for (int p = 0; p < 8; ++p) {
            const uint4 u = *(const uint4*)(hrow + (2 * pj + p) * 8);
            const f16x2 h0 = bc2(u.x), h1 = bc2(u.y), h2 = bc2(u.z), h3 = bc2(u.w);
            if (p <= 6) {
              const uint32_t* w = wq + p * 4;
              a0[rh][qq * 4 + 0] = __builtin_elementwise_fma(h0, bc2(w[0]), a0[rh][qq * 4 + 0]);
              a0[rh][qq * 4 + 1] = __builtin_elementwise_fma(h1, bc2(w[1]), a0[rh][qq * 4 + 1]);
              a0[rh][qq * 4 + 2] = __builtin_elementwise_fma(h2, bc2(w[2]), a0[rh][qq * 4 + 2]);
              a0[rh][qq * 4 + 3] = __builtin_elementwise_fma(h3, bc2(w[3]), a0[rh][qq * 4 + 3]);
            }
            if (p >= 1) {
              const uint32_t* w = wq + (p - 1) * 4;
              a1[rh][qq * 4 + 0] = __builtin_elementwise_fma(h0, bc2(w[0]), a1[rh][qq * 4 + 0]);
              a1[rh][qq * 4 + 1] = __builtin_elementwise_fma(h1, bc2(w[1]), a1[rh][qq * 4 + 1]);
              a1[rh][qq * 4 + 2] = __builtin_elementwise_fma(h2, bc2(w[2]), a1[rh][qq * 4 + 2]);
              a1[rh][qq * 4 + 3] = __builtin_elementwise_fma(h3, bc2(w[3]), a1[rh][qq * 4 + 3]);
            }
          }
        }
      }
    }

#pragma unroll
    for (int rh = 0; rh < 2; ++rh)
#pragma unroll
      for (int t = 0; t < 8; ++t) {
        s[rh][0] += (float)a0[rh][t].x + (float)a0[rh][t].y;
        s[rh][1] += (float)a1[rh][t].x + (float)a1[rh][t].y;
      }
    __syncthreads();   // before next phase overwrites htile
  }

  const float bias = b2[0];
#pragma unroll
  for (int rh = 0; rh < 2; ++rh) {
    const int i = i0 + li + rh * 16;
    const int j = j0 + 2 * pj;
    float2 o;
    o.x = (i < len && (j + 0) < len) ? s[rh][0] + bias : 0.f;
    o.y = (i < len && (j + 1) < len) ? s[rh][1] + bias : 0.f;
    *(float2*)(out + (size_t)(b * LL + i) * LL + j) = o;
  }
}

extern "C" void kernel_launch(void* const* d_in, const int* in_sizes, int n_in,
                              void* d_out, int out_size, void* d_ws, size_t ws_size,
                              hipStream_t stream) {
  const float* x   = (const float*)d_in[0];
  const int*   pl  = (const int*)d_in[1];
  const float* W1  = (const float*)d_in[2];
  const float* b1  = (const float*)d_in[3];
  const float* W2  = (const float*)d_in[4];
  const float* b2  = (const float*)d_in[5];
  float* out = (float*)d_out;

  _Float16* hws = (_Float16*)d_ws;                            // 33,554,432 B
  _Float16* w1p = (_Float16*)((char*)d_ws + 33554432);        // 32,768 B
  uint32_t* w2p = (uint32_t*)((char*)d_ws + 33587200);        // 3,136 B

  bepler_pack<<<dim3(65), dim3(256), 0, stream>>>(W1, W2, w1p, w2p);
  dim3 gA(8, 8, 16);   // (j-tile/32, i-tile/32, b*2 + ip-half)
  bepler_h_kernel<<<gA, dim3(256), 0, stream>>>(x, pl, (const uint4*)w1p, b1, hws);
  dim3 gB(8, 8, 8);    // (j-tile/32, i-tile/32, b)
  bepler_conv_kernel<<<gB, dim3(256), 0, stream>>>(hws, w2p, b2, pl, out);
}

// Round 4
// 109.900 us; speedup vs baseline: 1.1758x; 1.1758x over previous
//
#include <hip/hip_runtime.h>
#include <stdint.h>

#define LL 256
#define DD 256
#define CH 32

typedef __attribute__((ext_vector_type(2))) _Float16 f16x2;
typedef __attribute__((ext_vector_type(8))) _Float16 halfx8;
typedef __attribute__((ext_vector_type(4))) float f32x4;

static __device__ __forceinline__ uint32_t pk16(float a, float b) {
  f16x2 p; p.x = (_Float16)a; p.y = (_Float16)b;   // RTN casts
  return __builtin_bit_cast(uint32_t, p);
}
static __device__ __forceinline__ f16x2 bc2(uint32_t u) { return __builtin_bit_cast(f16x2, u); }
static __device__ __forceinline__ halfx8 bc8(uint4 u) { return __builtin_bit_cast(halfx8, u); }

// ---------------------------------------------------------------------------
// Kernel P: one-time packing.
//  blocks [0,256):   x fp32 -> xf f16 (8 elems/thread, coalesced float4 loads)
//  blocks [256,320): W1 -> w1p f16 in MFMA-A-frag layout with the d-permutation
//  block 320:        W2 -> w2a MFMA-A-frags: per kk (=dj), lane l:
//                    m = di = l&15 (rows 7..15 zero), k = c = 8*(l>>4)+e
// ---------------------------------------------------------------------------
__global__ void bepler_pack(const float* __restrict__ x, const float* __restrict__ W1,
                            const float* __restrict__ W2, _Float16* __restrict__ xf,
                            _Float16* __restrict__ w1p, uint4* __restrict__ w2a) {
  const int gid = blockIdx.x * 256 + threadIdx.x;
  if (blockIdx.x < 256) {
    const float4 f0 = ((const float4*)x)[gid * 2];
    const float4 f1 = ((const float4*)x)[gid * 2 + 1];
    uint4 v;
    v.x = pk16(f0.x, f0.y); v.y = pk16(f0.z, f0.w);
    v.z = pk16(f1.x, f1.y); v.w = pk16(f1.z, f1.w);
    ((uint4*)xf)[gid] = v;
  } else if (blockIdx.x < 320) {
    const int idx = gid - 65536;           // 0..16383
    const int t  = idx & 7;
    const int l  = (idx >> 3) & 63;
    const int hM = (idx >> 9) & 1;
    const int s  = idx >> 10;
    const int g  = (l >> 4) & 3;
    const int d  = 32 * (s >> 1) + 8 * g + 4 * (s & 1) + 2 * ((t >> 2) & 1) + (t & 1);
    const int ko = (t & 2) ? (DD + d) : d;
    w1p[idx] = (_Float16)W1[ko * CH + 16 * hM + (l & 15)];
  } else {
    for (int k = threadIdx.x; k < 7 * 64; k += 256) {
      const int kk = k >> 6, l = k & 63;
      const int m = l & 15;                // di (7..15 -> zero rows)
      const int cg = (l >> 4) * 8;         // channel base
      uint4 v = make_uint4(0u, 0u, 0u, 0u);
      if (m < 7) {
        const float* wsrc = W2 + ((m * 7) + kk) * 32 + cg;
        v.x = pk16(wsrc[0], wsrc[1]);
        v.y = pk16(wsrc[2], wsrc[3]);
        v.z = pk16(wsrc[4], wsrc[5]);
        v.w = pk16(wsrc[6], wsrc[7]);
      }
      w2a[k] = v;
    }
  }
}

// ---------------------------------------------------------------------------
// Kernel A: h[b,i,j,c] = mask * relu( z . W1[:,c] + b1[c] ), f16 out.
// (round-1 exact structure: xf pre-pack, length-cull, grid (8,8,8))
// ---------------------------------------------------------------------------
#define XPAD 272
__global__ __launch_bounds__(256, 2) void bepler_h_kernel(
    const _Float16* __restrict__ xf, const int* __restrict__ plen,
    const uint4* __restrict__ w1p4, const float* __restrict__ b1,
    _Float16* __restrict__ hws)
{
  __shared__ _Float16 xi[32 * XPAD];   // 17.4 KB
  __shared__ _Float16 xj[32 * XPAD];

  const int tid  = threadIdx.x;
  const int lane = tid & 63;
  const int wave = tid >> 6;
  const int b  = blockIdx.z;
  const int i0 = blockIdx.y * 32;
  const int j0 = blockIdx.x * 32;

  const int len = plen[b];
  if (i0 >= len || j0 >= len) return;   // block-uniform: whole tile is masked out

  const int g   = lane >> 4;
  const int m16 = lane & 15;

  // Load all 32 A-fragments from prepacked global (coalesced, L2-hot): 128 VGPR
  uint4 af[16][2];
#pragma unroll
  for (int s = 0; s < 16; ++s) {
#pragma unroll
    for (int hM = 0; hM < 2; ++hM)
      af[s][hM] = w1p4[(s * 2 + hM) * 64 + lane];
  }

  // Stage x tiles (pure uint4 copies from pre-converted xf)
  const _Float16* xfb = xf + (size_t)b * LL * DD;
  for (int idx = tid; idx < 1024; idx += 256) {
    const int r = idx >> 5, cg = idx & 31;
    ((uint4*)(xi + r * XPAD))[cg] = ((const uint4*)(xfb + (i0 + r) * DD))[cg];
    ((uint4*)(xj + r * XPAD))[cg] = ((const uint4*)(xfb + (j0 + r) * DD))[cg];
  }

  float b1v[2][4];
#pragma unroll
  for (int r = 0; r < 4; ++r) {
    b1v[0][r] = b1[g * 4 + r];
    b1v[1][r] = b1[16 + g * 4 + r];
  }
  __syncthreads();

  for (int ip = 0; ip < 4; ++ip) {       // i-row pairs
    const int r0 = wave * 8 + 2 * ip;
    const int r1 = r0 + 1;
    f32x4 acc[2][2][2];                  // [rr][jg][hM]
#pragma unroll
    for (int rr = 0; rr < 2; ++rr)
#pragma unroll
      for (int jg = 0; jg < 2; ++jg)
#pragma unroll
        for (int hM = 0; hM < 2; ++hM)
          acc[rr][jg][hM] = (f32x4){0.f, 0.f, 0.f, 0.f};

#pragma unroll
    for (int m = 0; m < 8; ++m) {
      const int doff = 32 * m + 8 * g;
      const uint4 ua0 = *(const uint4*)(xi + r0 * XPAD + doff);  // broadcast b128
      const uint4 ua1 = *(const uint4*)(xi + r1 * XPAD + doff);
#pragma unroll
      for (int jg = 0; jg < 2; ++jg) {
        const uint4 uc = *(const uint4*)(xj + (jg * 16 + m16) * XPAD + doff);
        const f16x2 c0 = bc2(uc.x), c1 = bc2(uc.y), c2 = bc2(uc.z), c3 = bc2(uc.w);
#pragma unroll
        for (int rr = 0; rr < 2; ++rr) {
          const uint4 ua = rr ? ua1 : ua0;
          const f16x2 a0 = bc2(ua.x), a1 = bc2(ua.y), a2 = bc2(ua.z), a3 = bc2(ua.w);
          const f16x2 p0 = a0 * c0, p1 = a1 * c1, p2 = a2 * c2, p3 = a3 * c3;
          const uint32_t s0 = __builtin_bit_cast(uint32_t, a0 - c0) & 0x7FFF7FFFu;
          const uint32_t s1 = __builtin_bit_cast(uint32_t, a1 - c1) & 0x7FFF7FFFu;
          const uint32_t s2 = __builtin_bit_cast(uint32_t, a2 - c2) & 0x7FFF7FFFu;
          const uint32_t s3 = __builtin_bit_cast(uint32_t, a3 - c3) & 0x7FFF7FFFu;
          uint4 be, bo;
          be.x = __builtin_bit_cast(uint32_t, p0); be.y = s0;
          be.z = __builtin_bit_cast(uint32_t, p1); be.w = s1;
          bo.x = __builtin_bit_cast(uint32_t, p2); bo.y = s2;
          bo.z = __builtin_bit_cast(uint32_t, p3); bo.w = s3;
          const halfx8 bE = bc8(be), bO = bc8(bo);
          acc[rr][jg][0] = __builtin_amdgcn_mfma_f32_16x16x32_f16(bc8(af[2 * m][0]),     bE, acc[rr][jg][0], 0, 0, 0);
          acc[rr][jg][1] = __builtin_amdgcn_mfma_f32_16x16x32_f16(bc8(af[2 * m][1]),     bE, acc[rr][jg][1], 0, 0, 0);
          acc[rr][jg][0] = __builtin_amdgcn_mfma_f32_16x16x32_f16(bc8(af[2 * m + 1][0]), bO, acc[rr][jg][0], 0, 0, 0);
          acc[rr][jg][1] = __builtin_amdgcn_mfma_f32_16x16x32_f16(bc8(af[2 * m + 1][1]), bO, acc[rr][jg][1], 0, 0, 0);
        }
      }
    }

    // D layout: c = 16*hM + (lane>>4)*4 + reg ; j = j0 + jg*16 + (lane&15)
#pragma unroll
    for (int rr = 0; rr < 2; ++rr) {
      const int i = i0 + (rr ? r1 : r0);
#pragma unroll
      for (int jg = 0; jg < 2; ++jg) {
        const int j = j0 + jg * 16 + m16;
        const float msk = (i < len && j < len) ? 1.f : 0.f;
        _Float16* hp = hws + ((size_t)(b * LL + i) * LL + j) * CH + g * 4;
#pragma unroll
        for (int hM = 0; hM < 2; ++hM) {
          const f32x4 a = acc[rr][jg][hM];
          uint2 st;
          st.x = pk16(fmaxf(a[0] + b1v[hM][0], 0.f) * msk,
                      fmaxf(a[1] + b1v[hM][1], 0.f) * msk);
          st.y = pk16(fmaxf(a[2] + b1v[hM][2], 0.f) * msk,
                      fmaxf(a[3] + b1v[hM][3], 0.f) * msk);
          *(uint2*)(hp + hM * 16) = st;
        }
      }
    }
  }
}

// ---------------------------------------------------------------------------
// Kernel B (MFMA conv): out[b,i,j] = mask*( sum_{di,dj,c} h*W2 + b2 )
// 16x16 out tile/block, halo 22x22x32ch in LDS (pos pitch 40 halfs -> 2-way
// banks max). Per halo row r: C[di,j] = sum_c W2[di,kk,c]*h[r,j+kk-3,c] via
// 7 chained mfma_16x16x32_f16 (kk = dj). Row r contributes to out i = r-di;
// wave w owns r = w+4t -> accumulator slot 4t-reg+3 is STATIC (no scratch).
// Cross-(wave,G) reduce via 12 KB LDS. f32 accumulation (>= old f16 accuracy).
// ---------------------------------------------------------------------------
#define HR 22
#define HC 22
#define PPITCH 40   // halfs per halo position (32 ch + 4-half pad -> 80 B)
__global__ __launch_bounds__(256, 3) void bepler_conv_kernel(
    const _Float16* __restrict__ hws, const uint4* __restrict__ w2a,
    const float* __restrict__ b2, const int* __restrict__ plen,
    float* __restrict__ out)
{
  __shared__ _Float16 htile[HR * HC * PPITCH];   // 38,720 B
  __shared__ float rbuf[4][2][24][16];           // 12,288 B

  const int tid = threadIdx.x;
  const int b   = blockIdx.z;
  const int i0  = blockIdx.y * 16;
  const int j0  = blockIdx.x * 16;
  const int l   = tid & 63;
  const int w   = tid >> 6;
  const int jt  = l & 15;
  const int G   = l >> 4;
  const int oi  = tid >> 4, oj = tid & 15;   // writeback ownership

  const int len = plen[b];
  if (i0 >= len || j0 >= len) {              // whole tile masked -> zero store
    out[(size_t)(b * LL + i0 + oi) * LL + j0 + oj] = 0.f;
    return;
  }

  // A-frags: lane l: m=di=l&15 (zero-padded >=7), k=c=8*(l>>4)+e
  uint4 af[7];
#pragma unroll
  for (int kk = 0; kk < 7; ++kk) af[kk] = w2a[kk * 64 + l];

  // zero rbuf (covers the one never-written-but-read slot) + stage halo
  for (int idx = tid; idx < 4 * 2 * 24 * 16; idx += 256) ((float*)rbuf)[idx] = 0.f;
  for (int idx = tid; idx < HR * HC * 4; idx += 256) {
    const int q = idx & 3, pos = idx >> 2;
    const int row = pos / HC, col = pos - row * HC;
    const int gi = i0 - 3 + row, gj = j0 - 3 + col;
    uint4 v = make_uint4(0u, 0u, 0u, 0u);
    if (gi >= 0 && gi < len && gj >= 0 && gj < len)
      v = *(const uint4*)(hws + ((size_t)(b * LL + gi) * LL + gj) * CH + q * 8);
    *(uint4*)(htile + pos * PPITCH + q * 8) = v;
  }
  __syncthreads();

  float acc[24];
#pragma unroll
  for (int s = 0; s < 24; ++s) acc[s] = 0.f;

#pragma unroll
  for (int t = 0; t < 6; ++t) {
    const int rl = w + 4 * t;                 // halo row handled by this wave
    if (rl < HR) {                            // wave-uniform guard
      const _Float16* base = htile + (rl * HC + jt) * PPITCH + 8 * G;
      f32x4 c = (f32x4){0.f, 0.f, 0.f, 0.f};
#pragma unroll
      for (int kk = 0; kk < 7; ++kk)
        c = __builtin_amdgcn_mfma_f32_16x16x32_f16(
              bc8(af[kk]), bc8(*(const uint4*)(base + kk * PPITCH)), c, 0, 0, 0);
      // D[m=4G+reg][j=jt]; out i = rl - di; slot = i - w + 4G + 3 = 4t - reg + 3
#pragma unroll
      for (int reg = 0; reg < 4; ++reg)
        acc[4 * t - reg + 3] += c[reg];
    }
  }

  if (G < 2) {                               // G>=2 rows are structurally zero
#pragma unroll
    for (int s = 0; s < 24; ++s) rbuf[w][G][s][jt] = acc[s];
  }
  __syncthreads();

  float sum = 0.f;
#pragma unroll
  for (int ww = 0; ww < 4; ++ww)
#pragma unroll
    for (int gg = 0; gg < 2; ++gg)
      sum += rbuf[ww][gg][oi + 3 - ww + 4 * gg][oj];

  const int gi = i0 + oi, gj = j0 + oj;
  out[(size_t)(b * LL + gi) * LL + gj] =
      (gi < len && gj < len) ? sum + b2[0] : 0.f;
}

extern "C" void kernel_launch(void* const* d_in, const int* in_sizes, int n_in,
                              void* d_out, int out_size, void* d_ws, size_t ws_size,
                              hipStream_t stream) {
  const float* x   = (const float*)d_in[0];
  const int*   pl  = (const int*)d_in[1];
  const float* W1  = (const float*)d_in[2];
  const float* b1  = (const float*)d_in[3];
  const float* W2  = (const float*)d_in[4];
  const float* b2  = (const float*)d_in[5];
  float* out = (float*)d_out;

  _Float16* hws = (_Float16*)d_ws;                            // 33,554,432 B
  _Float16* w1p = (_Float16*)((char*)d_ws + 33554432);        // 32,768 B
  uint4*    w2a = (uint4*)((char*)d_ws + 33587200);           // 7,168 B
  _Float16* xf  = (_Float16*)((char*)d_ws + 33594368);        // 1,048,576 B

  bepler_pack<<<dim3(321), dim3(256), 0, stream>>>(x, W1, W2, xf, w1p, w2a);
  dim3 gA(8, 8, 8);    // (j-tile/32, i-tile/32, b)
  bepler_h_kernel<<<gA, dim3(256), 0, stream>>>(xf, pl, (const uint4*)w1p, b1, hws);
  dim3 gB(16, 16, 8);  // (j-tile/16, i-tile/16, b)
  bepler_conv_kernel<<<gB, dim3(256), 0, stream>>>(hws, w2a, b2, pl, out);
}

// Round 5
// 100.801 us; speedup vs baseline: 1.2820x; 1.0903x over previous
//
#include <hip/hip_runtime.h>
#include <stdint.h>

#define LL 256
#define DD 256
#define CH 32
#define OT 26        // output tile (per block)
#define HT 32        // halo tile = OT + 6
#define PPH 20       // halfs per halo position in LDS (16 ch + 4 pad)
#define XPAD 272

typedef __attribute__((ext_vector_type(2))) _Float16 f16x2;
typedef __attribute__((ext_vector_type(4))) _Float16 halfx4;
typedef __attribute__((ext_vector_type(8))) _Float16 halfx8;
typedef __attribute__((ext_vector_type(4))) float f32x4;

static __device__ __forceinline__ uint32_t pk16(float a, float b) {
  f16x2 p; p.x = (_Float16)a; p.y = (_Float16)b;   // RTN casts
  return __builtin_bit_cast(uint32_t, p);
}
static __device__ __forceinline__ f16x2 bc2(uint32_t u) { return __builtin_bit_cast(f16x2, u); }
static __device__ __forceinline__ halfx4 bc4(uint2 u) { return __builtin_bit_cast(halfx4, u); }
static __device__ __forceinline__ halfx8 bc8(uint4 u) { return __builtin_bit_cast(halfx8, u); }

// ---------------------------------------------------------------------------
// Kernel P: one-time packing.
//  blocks [0,256):   x fp32 -> xf f16
//  blocks [256,320): W1 -> w1p f16 MFMA-A-frags (d-permutation), as before
//  block 320:        W2 -> w2b 16x16x16 A-frags: per (ph,kk), lane l:
//                    m = di = l&15 (rows 7..15 zero), k = 4*(l>>4)+e,
//                    channel = ph*16 + 4*(l>>4) + e
// ---------------------------------------------------------------------------
__global__ void bepler_pack(const float* __restrict__ x, const float* __restrict__ W1,
                            const float* __restrict__ W2, _Float16* __restrict__ xf,
                            _Float16* __restrict__ w1p, uint2* __restrict__ w2b) {
  const int gid = blockIdx.x * 256 + threadIdx.x;
  if (blockIdx.x < 256) {
    const float4 f0 = ((const float4*)x)[gid * 2];
    const float4 f1 = ((const float4*)x)[gid * 2 + 1];
    uint4 v;
    v.x = pk16(f0.x, f0.y); v.y = pk16(f0.z, f0.w);
    v.z = pk16(f1.x, f1.y); v.w = pk16(f1.z, f1.w);
    ((uint4*)xf)[gid] = v;
  } else if (blockIdx.x < 320) {
    const int idx = gid - 65536;           // 0..16383
    const int t  = idx & 7;
    const int l  = (idx >> 3) & 63;
    const int hM = (idx >> 9) & 1;
    const int s  = idx >> 10;
    const int g  = (l >> 4) & 3;
    const int d  = 32 * (s >> 1) + 8 * g + 4 * (s & 1) + 2 * ((t >> 2) & 1) + (t & 1);
    const int ko = (t & 2) ? (DD + d) : d;
    w1p[idx] = (_Float16)W1[ko * CH + 16 * hM + (l & 15)];
  } else {
    for (int k = threadIdx.x; k < 2 * 7 * 64; k += 256) {
      const int l  = k & 63;
      const int kk = (k >> 6) % 7;
      const int ph = k / 448;
      const int di = l & 15;
      const int G  = l >> 4;
      uint2 v = make_uint2(0u, 0u);
      if (di < 7) {
        const float* ws = W2 + ((di * 7) + kk) * 32 + ph * 16 + G * 4;
        v.x = pk16(ws[0], ws[1]);
        v.y = pk16(ws[2], ws[3]);
      }
      w2b[k] = v;
    }
  }
}

// ---------------------------------------------------------------------------
// FUSED kernel: per 26x26 out tile, compute the 32x32 h halo tile in LDS
// (identical MFMA pipeline to the verified kernel A), then 7x7 conv via
// mfma_16x16x16 in two 16-channel phases. h never touches global memory.
//  - x staging rows clamped; h mask (0<=gi<len etc.) zeroes halo exactly.
//  - phase-1 h halves held in 16 uint2 regs between conv phases.
//  - scatter slots s = 4t-reg+3 (bijection over [0,32)); reduce reads
//    rb[ww][gg][oi-ww+4gg+3][oj]; invalid combos hit zero-padded W2 rows.
//  - rb (32 KB) aliases the x staging buffer (34.8 KB) after its last read.
// LDS: 41,280 (hts) + 34,816 (ubuf) = 76,096 B -> 2 blocks/CU.
// ---------------------------------------------------------------------------
__global__ __launch_bounds__(256, 2) void bepler_fused(
    const _Float16* __restrict__ xf, const int* __restrict__ plen,
    const uint4* __restrict__ w1p4, const float* __restrict__ b1,
    const uint2* __restrict__ w2b, const float* __restrict__ b2,
    float* __restrict__ out)
{
  __shared__ _Float16 hts[HT * HT * PPH + 8 * PPH];       // 41,280 B (+pad)
  __shared__ __align__(16) char ubuf[2 * 32 * XPAD * 2];  // 34,816 B
  _Float16* xi = (_Float16*)ubuf;
  _Float16* xj = xi + 32 * XPAD;
  float (*rb)[2][32][32] = (float (*)[2][32][32])ubuf;    // 32,768 B alias

  const int tid  = threadIdx.x;
  const int lane = tid & 63;
  const int wv   = tid >> 6;
  const int b    = blockIdx.z;
  const int oi0  = blockIdx.y * OT;
  const int oj0  = blockIdx.x * OT;
  const int hi0  = oi0 - 3, hj0 = oj0 - 3;
  const int len  = plen[b];
  const float bias = b2[0];

  if (oi0 >= len || oj0 >= len) {        // whole out tile masked -> zeros
    for (int p = tid; p < OT * OT; p += 256) {
      const int gi = oi0 + p / OT, gj = oj0 + p % OT;
      if (gi < LL && gj < LL) out[(size_t)(b * LL + gi) * LL + gj] = 0.f;
    }
    return;
  }

  const int g   = lane >> 4;
  const int m16 = lane & 15;

  // W1 A-frags from prepacked global (L2-hot): 128 VGPR
  uint4 af[16][2];
#pragma unroll
  for (int s = 0; s < 16; ++s) {
#pragma unroll
    for (int hM = 0; hM < 2; ++hM)
      af[s][hM] = w1p4[(s * 2 + hM) * 64 + lane];
  }

  // Stage x halo rows (clamped; invalid rows masked to 0 in h below)
  const _Float16* xfb = xf + (size_t)b * LL * DD;
  for (int idx = tid; idx < 1024; idx += 256) {
    const int r = idx >> 5, cg = idx & 31;
    int ri = hi0 + r; ri = ri < 0 ? 0 : (ri > LL - 1 ? LL - 1 : ri);
    int rj = hj0 + r; rj = rj < 0 ? 0 : (rj > LL - 1 ? LL - 1 : rj);
    ((uint4*)(xi + r * XPAD))[cg] = ((const uint4*)(xfb + ri * DD))[cg];
    ((uint4*)(xj + r * XPAD))[cg] = ((const uint4*)(xfb + rj * DD))[cg];
  }

  float b1v[2][4];
#pragma unroll
  for (int r = 0; r < 4; ++r) {
    b1v[0][r] = b1[g * 4 + r];
    b1v[1][r] = b1[16 + g * 4 + r];
  }
  __syncthreads();

  // ---- A-phase: h halo tile -> LDS (phase-0 ch) + regs (phase-1 ch) ----
  uint2 accH1p[16];                      // [ip*4 + jg*2 + rr], static idx
#pragma unroll
  for (int ip = 0; ip < 4; ++ip) {
    const int r0 = wv * 8 + 2 * ip;
    const int r1 = r0 + 1;
    f32x4 acc[2][2][2];                  // [rr][jg][hM]
#pragma unroll
    for (int rr = 0; rr < 2; ++rr)
#pragma unroll
      for (int jg = 0; jg < 2; ++jg)
#pragma unroll
        for (int hM = 0; hM < 2; ++hM)
          acc[rr][jg][hM] = (f32x4){0.f, 0.f, 0.f, 0.f};

#pragma unroll
    for (int m = 0; m < 8; ++m) {
      const int doff = 32 * m + 8 * g;
      const uint4 ua0 = *(const uint4*)(xi + r0 * XPAD + doff);
      const uint4 ua1 = *(const uint4*)(xi + r1 * XPAD + doff);
#pragma unroll
      for (int jg = 0; jg < 2; ++jg) {
        const uint4 uc = *(const uint4*)(xj + (jg * 16 + m16) * XPAD + doff);
        const f16x2 c0 = bc2(uc.x), c1 = bc2(uc.y), c2 = bc2(uc.z), c3 = bc2(uc.w);
#pragma unroll
        for (int rr = 0; rr < 2; ++rr) {
          const uint4 ua = rr ? ua1 : ua0;
          const f16x2 a0 = bc2(ua.x), a1 = bc2(ua.y), a2v = bc2(ua.z), a3 = bc2(ua.w);
          const f16x2 p0 = a0 * c0, p1 = a1 * c1, p2 = a2v * c2, p3 = a3 * c3;
          const uint32_t s0 = __builtin_bit_cast(uint32_t, a0 - c0) & 0x7FFF7FFFu;
          const uint32_t s1 = __builtin_bit_cast(uint32_t, a1 - c1) & 0x7FFF7FFFu;
          const uint32_t s2 = __builtin_bit_cast(uint32_t, a2v - c2) & 0x7FFF7FFFu;
          const uint32_t s3 = __builtin_bit_cast(uint32_t, a3 - c3) & 0x7FFF7FFFu;
          uint4 be, bo;
          be.x = __builtin_bit_cast(uint32_t, p0); be.y = s0;
          be.z = __builtin_bit_cast(uint32_t, p1); be.w = s1;
          bo.x = __builtin_bit_cast(uint32_t, p2); bo.y = s2;
          bo.z = __builtin_bit_cast(uint32_t, p3); bo.w = s3;
          const halfx8 bE = bc8(be), bO = bc8(bo);
          acc[rr][jg][0] = __builtin_amdgcn_mfma_f32_16x16x32_f16(bc8(af[2 * m][0]),     bE, acc[rr][jg][0], 0, 0, 0);
          acc[rr][jg][1] = __builtin_amdgcn_mfma_f32_16x16x32_f16(bc8(af[2 * m][1]),     bE, acc[rr][jg][1], 0, 0, 0);
          acc[rr][jg][0] = __builtin_amdgcn_mfma_f32_16x16x32_f16(bc8(af[2 * m + 1][0]), bO, acc[rr][jg][0], 0, 0, 0);
          acc[rr][jg][1] = __builtin_amdgcn_mfma_f32_16x16x32_f16(bc8(af[2 * m + 1][1]), bO, acc[rr][jg][1], 0, 0, 0);
        }
      }
    }

    // relu+bias+mask, pack: phase-0 -> LDS, phase-1 -> regs
#pragma unroll
    for (int rr = 0; rr < 2; ++rr) {
      const int rloc = rr ? r1 : r0;
      const int gi = hi0 + rloc;
#pragma unroll
      for (int jg = 0; jg < 2; ++jg) {
        const int jl = jg * 16 + m16;
        const int gj = hj0 + jl;
        const float msk = (gi >= 0 && gi < len && gj >= 0 && gj < len) ? 1.f : 0.f;
        {
          const f32x4 a = acc[rr][jg][0];
          uint2 st;
          st.x = pk16(fmaxf(a[0] + b1v[0][0], 0.f) * msk, fmaxf(a[1] + b1v[0][1], 0.f) * msk);
          st.y = pk16(fmaxf(a[2] + b1v[0][2], 0.f) * msk, fmaxf(a[3] + b1v[0][3], 0.f) * msk);
          *(uint2*)(hts + (rloc * HT + jl) * PPH + g * 4) = st;
        }
        {
          const f32x4 a = acc[rr][jg][1];
          uint2 st;
          st.x = pk16(fmaxf(a[0] + b1v[1][0], 0.f) * msk, fmaxf(a[1] + b1v[1][1], 0.f) * msk);
          st.y = pk16(fmaxf(a[2] + b1v[1][2], 0.f) * msk, fmaxf(a[3] + b1v[1][3], 0.f) * msk);
          accH1p[ip * 4 + jg * 2 + rr] = st;
        }
      }
    }
  }
  __syncthreads();

  // ---- conv phase 0 (channels 0..15) ----
  float a2[2][32];
#pragma unroll
  for (int js = 0; js < 2; ++js)
#pragma unroll
    for (int s = 0; s < 32; ++s) a2[js][s] = 0.f;

  {
    uint2 wf[7];
#pragma unroll
    for (int kk = 0; kk < 7; ++kk) wf[kk] = w2b[kk * 64 + lane];
#pragma unroll
    for (int t = 0; t < 8; ++t) {
      const int r = wv + 4 * t;            // halo row 0..31
#pragma unroll
      for (int js = 0; js < 2; ++js) {
        const _Float16* base = hts + (r * HT + js * 16 + m16) * PPH + g * 4;
        f32x4 c = (f32x4){0.f, 0.f, 0.f, 0.f};
#pragma unroll
        for (int kk = 0; kk < 7; ++kk)
          c = __builtin_amdgcn_mfma_f32_16x16x16f16(bc4(wf[kk]), bc4(*(const uint2*)(base + kk * PPH)), c, 0, 0, 0);
#pragma unroll
        for (int reg = 0; reg < 4; ++reg)
          a2[js][4 * t - reg + 3] += c[reg];
      }
    }
  }
  __syncthreads();

  // ---- write h phase-1 halves (channels 16..31) into hts ----
#pragma unroll
  for (int ip = 0; ip < 4; ++ip)
#pragma unroll
    for (int rr = 0; rr < 2; ++rr)
#pragma unroll
      for (int jg = 0; jg < 2; ++jg) {
        const int rloc = wv * 8 + 2 * ip + rr;
        const int jl = jg * 16 + m16;
        *(uint2*)(hts + (rloc * HT + jl) * PPH + g * 4) = accH1p[ip * 4 + jg * 2 + rr];
      }
  __syncthreads();

  // ---- conv phase 1 (channels 16..31) ----
  {
    uint2 wf[7];
#pragma unroll
    for (int kk = 0; kk < 7; ++kk) wf[kk] = w2b[448 + kk * 64 + lane];
#pragma unroll
    for (int t = 0; t < 8; ++t) {
      const int r = wv + 4 * t;
#pragma unroll
      for (int js = 0; js < 2; ++js) {
        const _Float16* base = hts + (r * HT + js * 16 + m16) * PPH + g * 4;
        f32x4 c = (f32x4){0.f, 0.f, 0.f, 0.f};
#pragma unroll
        for (int kk = 0; kk < 7; ++kk)
          c = __builtin_amdgcn_mfma_f32_16x16x16f16(bc4(wf[kk]), bc4(*(const uint2*)(base + kk * PPH)), c, 0, 0, 0);
#pragma unroll
        for (int reg = 0; reg < 4; ++reg)
          a2[js][4 * t - reg + 3] += c[reg];
      }
    }
  }

  // ---- scatter to reduce buffer (aliases dead x staging) ----
  if (g < 2) {
#pragma unroll
    for (int s = 0; s < 32; ++s) {
      rb[wv][g][s][m16]      = a2[0][s];
      rb[wv][g][s][16 + m16] = a2[1][s];
    }
  }
  __syncthreads();

  // ---- reduce + store ----
  for (int p = tid; p < OT * OT; p += 256) {
    const int oi = p / OT, oj = p - (p / OT) * OT;
    float sum = 0.f;
#pragma unroll
    for (int ww = 0; ww < 4; ++ww)
#pragma unroll
      for (int gg = 0; gg < 2; ++gg) {
        const int s = oi - ww + 4 * gg + 3;
        if (s < 32) sum += rb[ww][gg][s][oj];
      }
    const int gi = oi0 + oi, gj = oj0 + oj;
    if (gi < LL && gj < LL)
      out[(size_t)(b * LL + gi) * LL + gj] = (gi < len && gj < len) ? sum + bias : 0.f;
  }
}

extern "C" void kernel_launch(void* const* d_in, const int* in_sizes, int n_in,
                              void* d_out, int out_size, void* d_ws, size_t ws_size,
                              hipStream_t stream) {
  const float* x   = (const float*)d_in[0];
  const int*   pl  = (const int*)d_in[1];
  const float* W1  = (const float*)d_in[2];
  const float* b1  = (const float*)d_in[3];
  const float* W2  = (const float*)d_in[4];
  const float* b2  = (const float*)d_in[5];
  float* out = (float*)d_out;

  _Float16* w1p = (_Float16*)d_ws;                      // 32,768 B
  uint2*    w2b = (uint2*)((char*)d_ws + 32768);        // 7,168 B
  _Float16* xf  = (_Float16*)((char*)d_ws + 65536);     // 1,048,576 B

  bepler_pack<<<dim3(321), dim3(256), 0, stream>>>(x, W1, W2, xf, w1p, w2b);
  dim3 gF(10, 10, 8);  // (j-tile/26, i-tile/26, b)
  bepler_fused<<<gF, dim3(256), 0, stream>>>(xf, pl, (const uint4*)w1p, b1, w2b, b2, out);
}